// Round 4
// baseline (1864.243 us; speedup 1.0000x reference)
//
#include <hip/hip_runtime.h>
#include <hip/hip_bf16.h>

typedef _Float16 half8 __attribute__((ext_vector_type(8)));
typedef _Float16 half4 __attribute__((ext_vector_type(4)));
typedef float    floatx4 __attribute__((ext_vector_type(4)));

#define B_TOT 4096
#define L_SEQ 2048
#define H_DIM 256
#define FUT   128
#define T_TOT (L_SEQ + FUT)   /* 2176 */
#define ROWS  16              /* batch rows per block */
#define CHUNK 128             /* x prefetch chunk (steps) */

// tanh(p) = 1 - 2/(e^{2p}+1); exp2 overflow/underflow give exact +-1.
__device__ __forceinline__ float tanh_fast(float p) {
    float e = __builtin_amdgcn_exp2f(p * 2.885390082f);     // e^(2p)
    return __builtin_fmaf(-2.0f, __builtin_amdgcn_rcpf(e + 1.0f), 1.0f);
}

// 4 waves x 4 N-tiles each (was 8x2): per-CU LDS h-broadcast traffic halves
// (the B-fragments are identical across waves; fewer waves = fewer duplicate
// reads).  1 wave/SIMD, ~280 VGPR/wave -> W_hh lives entirely in registers.
// C = W_tile(A) @ h^T(B); C col = batch row, C row = 4 consecutive neurons ->
// packed ds_write_b64.  lin = 17th MFMA tile on wave 0.  Outputs ring-buffer
// in LDS, coalesced flush every 32 steps.
__global__ __launch_bounds__(256, 1) void rnn_seq_kernel(
    const float* __restrict__ x,      // [B, L]
    const float* __restrict__ W_ih,   // [H]
    const float* __restrict__ b_ih,   // [H]
    const float* __restrict__ W_hh,   // [H, H]
    const float* __restrict__ b_hh,   // [H]
    const float* __restrict__ W_lin,  // [H]
    const float* __restrict__ b_lin,  // [1]
    float* __restrict__ out)          // [B, T_TOT]
{
    __shared__ __align__(16) unsigned char hbuf[2][ROWS * H_DIM * 2]; // fp16 dbuf
    __shared__ __align__(16) float xbuf[CHUNK * 17];                  // [t_local][row] padded
    __shared__ __align__(16) float obuf2[2][32][17];                  // out ring, padded

    const int tid  = threadIdx.x;
    const int l    = tid & 63;
    const int w    = tid >> 6;       // wave 0..3
    const int ln15 = l & 15;
    const int lg   = l >> 4;         // 0..3
    const int b0   = blockIdx.x * ROWS;

    // ---- loop-invariant register state ----
    half8 wf[4][8];                   // W_hh A-frags: 4 N-tiles per wave
    #pragma unroll
    for (int i = 0; i < 4; ++i) {
        const int n = (4 * w + i) * 16 + ln15;
        #pragma unroll
        for (int kk = 0; kk < 8; ++kk) {
            const float* p = W_hh + n * H_DIM + kk * 32 + lg * 8;
            half8 v;
            #pragma unroll
            for (int j = 0; j < 8; ++j) v[j] = (_Float16)p[j];
            wf[i][kk] = v;
        }
    }
    half8 wlf[8];                     // W_lin A-frag (row 0), wave 0 only
    #pragma unroll
    for (int kk = 0; kk < 8; ++kk) {
        const int kbase = kk * 32 + lg * 8;
        half8 v;
        #pragma unroll
        for (int j = 0; j < 8; ++j)
            v[j] = (ln15 == 0) ? (_Float16)W_lin[kbase + j] : (_Float16)0.0f;
        wlf[kk] = v;
    }
    floatx4 wih4[4], bia4[4];
    #pragma unroll
    for (int i = 0; i < 4; ++i) {
        const int n0 = (4 * w + i) * 16 + lg * 4;
        #pragma unroll
        for (int r = 0; r < 4; ++r) {
            wih4[i][r] = W_ih[n0 + r];
            bia4[i][r] = b_ih[n0 + r] + b_hh[n0 + r];
        }
    }
    const float blin = b_lin[0];

    // LDS byte offsets (XOR swizzle bits 4-6 keyed by row&7)
    int aoff[8];
    #pragma unroll
    for (int kk = 0; kk < 8; ++kk)
        aoff[kk] = (ln15 * 512 + kk * 64 + lg * 16) ^ ((ln15 & 7) << 4);
    int woff4[4];
    #pragma unroll
    for (int i = 0; i < 4; ++i)
        woff4[i] = (ln15 * 512 + (4 * w + i) * 32 + lg * 8) ^ ((ln15 & 7) << 4);

    // h0 = 0 (8 KB over 256 threads)
    *(floatx4*)(hbuf[0] + tid * 32)      = floatx4{0.f, 0.f, 0.f, 0.f};
    *(floatx4*)(hbuf[0] + tid * 32 + 16) = floatx4{0.f, 0.f, 0.f, 0.f};
    __syncthreads();

    int cur = 0;

    // ============================ main phase ============================
    for (int s = 1; s <= L_SEQ; ++s) {
        const int t_out = s - 2;
        if (t_out >= 32 && (t_out & 31) == 0) {       // coalesced ring flush
            const int tb = t_out - 32, par = (tb >> 5) & 1;
            const int tt = tid & 31;
            #pragma unroll
            for (int jj = 0; jj < 2; ++jj) {
                const int row = (tid >> 5) + 8 * jj;
                out[(size_t)(b0 + row) * T_TOT + tb + tt] = obuf2[par][tt][row] + blin;
            }
        }
        if (((s - 1) & (CHUNK - 1)) == 0) {           // x chunk prefetch
            #pragma unroll
            for (int jj = 0; jj < 8; ++jj) {
                const int idx = jj * 256 + tid;
                const int row = idx >> 7, tl = idx & 127;
                xbuf[tl * 17 + row] = x[(size_t)(b0 + row) * L_SEQ + (s - 1) + tl];
            }
            __syncthreads();
        }
        const float xm = xbuf[((s - 1) & (CHUNK - 1)) * 17 + ln15];

        half8 a[8];                                    // B-frags of h_{s-1}
        #pragma unroll
        for (int kk = 0; kk < 8; ++kk)
            a[kk] = *(const half8*)(hbuf[cur] + aoff[kk]);

        floatx4 acc[4];                                // init = fma(x, W_ih, b)
        #pragma unroll
        for (int i = 0; i < 4; ++i)
            #pragma unroll
            for (int r = 0; r < 4; ++r)
                acc[i][r] = __builtin_fmaf(xm, wih4[i][r], bia4[i][r]);
        #pragma unroll
        for (int kk = 0; kk < 8; ++kk) {
            #pragma unroll
            for (int i = 0; i < 4; ++i)
                acc[i] = __builtin_amdgcn_mfma_f32_16x16x32_f16(wf[i][kk], a[kk], acc[i], 0, 0, 0);
        }
        if (w == 0) {                                  // lin tile
            floatx4 al = floatx4{0, 0, 0, 0};
            #pragma unroll
            for (int kk = 0; kk < 8; ++kk)
                al = __builtin_amdgcn_mfma_f32_16x16x32_f16(wlf[kk], a[kk], al, 0, 0, 0);
            if (lg == 0 && s >= 2)
                obuf2[(t_out >> 5) & 1][t_out & 31][ln15] = al[0];
        }
        #pragma unroll
        for (int i = 0; i < 4; ++i) {                  // tanh + packed h-write
            half4 hv;
            #pragma unroll
            for (int r = 0; r < 4; ++r) hv[r] = (_Float16)tanh_fast(acc[i][r]);
            *(half4*)(hbuf[cur ^ 1] + woff4[i]) = hv;
        }
        __syncthreads();
        cur ^= 1;
    }

    // ============================ future phase ============================
    for (int s = L_SEQ + 1; s <= T_TOT; ++s) {
        const int t_out = s - 2;
        if ((t_out & 31) == 0) {                       // ring flush
            const int tb = t_out - 32, par = (tb >> 5) & 1;
            const int tt = tid & 31;
            #pragma unroll
            for (int jj = 0; jj < 2; ++jj) {
                const int row = (tid >> 5) + 8 * jj;
                out[(size_t)(b0 + row) * T_TOT + tb + tt] = obuf2[par][tt][row] + blin;
            }
        }
        half8 a[8];
        #pragma unroll
        for (int kk = 0; kk < 8; ++kk)
            a[kk] = *(const half8*)(hbuf[cur] + aoff[kk]);

        floatx4 al = floatx4{0, 0, 0, 0};              // lin FIRST on wave 0
        if (w == 0) {
            #pragma unroll
            for (int kk = 0; kk < 8; ++kk)
                al = __builtin_amdgcn_mfma_f32_16x16x32_f16(wlf[kk], a[kk], al, 0, 0, 0);
            if (lg == 0)
                obuf2[(t_out >> 5) & 1][t_out & 31][ln15] = al[0];
        }
        floatx4 acc[4];
        #pragma unroll
        for (int i = 0; i < 4; ++i) acc[i] = bia4[i];
        #pragma unroll
        for (int kk = 0; kk < 8; ++kk) {
            #pragma unroll
            for (int i = 0; i < 4; ++i)
                acc[i] = __builtin_amdgcn_mfma_f32_16x16x32_f16(wf[i][kk], a[kk], acc[i], 0, 0, 0);
        }
        __syncthreads();                               // fed-back output visible
        const float xm = obuf2[(t_out >> 5) & 1][t_out & 31][ln15] + blin;

        #pragma unroll
        for (int i = 0; i < 4; ++i) {
            half4 hv;
            #pragma unroll
            for (int r = 0; r < 4; ++r)
                hv[r] = (_Float16)tanh_fast(__builtin_fmaf(xm, wih4[i][r], acc[i][r]));
            *(half4*)(hbuf[cur ^ 1] + woff4[i]) = hv;
        }
        __syncthreads();
        cur ^= 1;
    }

    // final out t = 2175 = lin(h_final): one more lin tile on wave 0
    if (w == 0) {
        half8 a[8];
        #pragma unroll
        for (int kk = 0; kk < 8; ++kk)
            a[kk] = *(const half8*)(hbuf[cur] + aoff[kk]);
        floatx4 al = floatx4{0, 0, 0, 0};
        #pragma unroll
        for (int kk = 0; kk < 8; ++kk)
            al = __builtin_amdgcn_mfma_f32_16x16x32_f16(wlf[kk], a[kk], al, 0, 0, 0);
        if (lg == 0) obuf2[1][31][ln15] = al[0];
    }
    __syncthreads();
    {   // final flush t = 2144..2175 (parity 1)
        const int tt = tid & 31;
        #pragma unroll
        for (int jj = 0; jj < 2; ++jj) {
            const int row = (tid >> 5) + 8 * jj;
            out[(size_t)(b0 + row) * T_TOT + 2144 + tt] = obuf2[1][tt][row] + blin;
        }
    }
}

extern "C" void kernel_launch(void* const* d_in, const int* in_sizes, int n_in,
                              void* d_out, int out_size, void* d_ws, size_t ws_size,
                              hipStream_t stream) {
    const float* x     = (const float*)d_in[0];
    const float* W_ih  = (const float*)d_in[1];
    const float* b_ih  = (const float*)d_in[2];
    const float* W_hh  = (const float*)d_in[3];
    const float* b_hh  = (const float*)d_in[4];
    const float* W_lin = (const float*)d_in[5];
    const float* b_lin = (const float*)d_in[6];
    float* out = (float*)d_out;
    rnn_seq_kernel<<<B_TOT / ROWS, 256, 0, stream>>>(x, W_ih, b_ih, W_hh, b_hh, W_lin, b_lin, out);
}